// Round 8
// baseline (174.898 us; speedup 1.0000x reference)
//
#include <hip/hip_runtime.h>

static constexpr int kN   = 50000;    // nodes
static constexpr int kNR  = 100000;   // N*D rows
static constexpr int kE0  = 200000;   // original edges
static constexpr int kE2  = 400000;   // directed edges
static constexpr int kCAP = 32;       // adjacency capacity per node (Poisson(8): P(>=32)~7e-11)

typedef _Float16 f16;
typedef f16   f16x8 __attribute__((ext_vector_type(8)));
typedef f16   f16x4 __attribute__((ext_vector_type(4)));
typedef float f32x4 __attribute__((ext_vector_type(4)));

// ---------------------------------------------------------------------------
// k_wrh: one-shot fp32 -> f16 conversion of W_right (128x128, L2-resident)
// ---------------------------------------------------------------------------
__global__ __launch_bounds__(256) void k_wrh(
    const float* __restrict__ Wr, f16* __restrict__ Wrh)
{
    const int i = blockIdx.x * 256 + threadIdx.x;   // 16384 elements
    Wrh[i] = (f16)Wr[i];
}

// ---------------------------------------------------------------------------
// k_node: per block = 32 nodes (64 rows).
//  - computes a[n][2], b[n][2]  (sheaf projections, fp32 wave reductions)
//  - tmp = W_left-mix of x (per row) -> LDS fp16 (A operand only; 17.4 KB)
//  - GEMM: xb[row][c] = - sum_k tmp[row][k] * W_right[c][k] via MFMA f16,
//    B-fragments loaded directly from global Wrh (L2-hot, no LDS, no barrier)
//  - in-wave LDS repack -> coalesced fp16 stores of xb
// ---------------------------------------------------------------------------
__global__ __launch_bounds__(256) void k_node(
    const float* __restrict__ x, const float* __restrict__ Wsh,
    const float* __restrict__ Wl, const f16* __restrict__ Wrh,
    f16* __restrict__ xb, float4* __restrict__ ab)
{
    __shared__ f16 Al[64][136];    // tmp rows / later output repack (+8 pad)

    const int t   = threadIdx.x;
    const int blk = blockIdx.x;

    const float wl00 = Wl[0], wl01 = Wl[1], wl10 = Wl[2], wl11 = Wl[3];

    const int w = t >> 6, lane = t & 63;

    // stage tmp into LDS + compute a/b projections
    #pragma unroll
    for (int i = 0; i < 8; ++i) {
        const int f4   = i * 256 + t;        // float4 index in 64x128 tile
        const int row  = f4 >> 5;            // 0..63
        const int h4   = (f4 & 31) << 2;     // 0..124
        const int grow = blk * 64 + row;
        float4 xo = make_float4(0.f, 0.f, 0.f, 0.f);
        float4 xp = xo;
        if (grow < kNR) {
            xo = *(const float4*)(x + (size_t)grow * 128 + h4);
            xp = *(const float4*)(x + (size_t)(grow ^ 1) * 128 + h4);
        }
        const int dp = row & 1;
        const float  c0 = dp ? wl10 : wl00;
        const float  c1 = dp ? wl11 : wl01;
        const float4 x0 = dp ? xp : xo;      // d2 = 0 data
        const float4 x1 = dp ? xo : xp;      // d2 = 1 data
        Al[row][h4 + 0] = (f16)(c0 * x0.x + c1 * x1.x);
        Al[row][h4 + 1] = (f16)(c0 * x0.y + c1 * x1.y);
        Al[row][h4 + 2] = (f16)(c0 * x0.z + c1 * x1.z);
        Al[row][h4 + 3] = (f16)(c0 * x0.w + c1 * x1.w);

        // a/b partials from OWN float4 (k = dp*128 + h4)
        const int kb = dp * 128 + h4;
        const float4 wa0 = *(const float4*)(Wsh + kb);
        const float4 wb0 = *(const float4*)(Wsh + 256 + kb);
        const float4 wa1 = *(const float4*)(Wsh + 512 + kb);
        const float4 wb1 = *(const float4*)(Wsh + 768 + kb);
        float pa0 = xo.x*wa0.x + xo.y*wa0.y + xo.z*wa0.z + xo.w*wa0.w;
        float pa1 = xo.x*wa1.x + xo.y*wa1.y + xo.z*wa1.z + xo.w*wa1.w;
        float pb0 = xo.x*wb0.x + xo.y*wb0.y + xo.z*wb0.z + xo.w*wb0.w;
        float pb1 = xo.x*wb1.x + xo.y*wb1.y + xo.z*wb1.z + xo.w*wb1.w;
        #pragma unroll
        for (int o = 32; o > 0; o >>= 1) {
            pa0 += __shfl_xor(pa0, o);
            pa1 += __shfl_xor(pa1, o);
            pb0 += __shfl_xor(pb0, o);
            pb1 += __shfl_xor(pb1, o);
        }
        if (lane == 0) {
            const int node = blk * 32 + i * 4 + w;
            if (node < kN) ab[node] = make_float4(pa0, pa1, pb0, pb1);
        }
    }
    __syncthreads();

    // MFMA: each wave does 16 rows x 128 cols, K=128
    const int lr = lane & 15, lk = lane >> 4;
    f16x8 afr[4];
    #pragma unroll
    for (int kk = 0; kk < 4; ++kk)
        afr[kk] = *(const f16x8*)&Al[16 * w + lr][kk * 32 + lk * 8];

    f32x4 accs[8];
    #pragma unroll
    for (int j = 0; j < 8; ++j) {
        f32x4 acc = {0.f, 0.f, 0.f, 0.f};
        #pragma unroll
        for (int kk = 0; kk < 4; ++kk) {
            const f16x8 bfr = *(const f16x8*)(Wrh + (size_t)(j * 16 + lr) * 128 + kk * 32 + lk * 8);
            acc = __builtin_amdgcn_mfma_f32_16x16x32_f16(afr[kk], bfr, acc, 0, 0, 0);
        }
        accs[j] = acc;
    }

    __syncthreads();
    // repack: write -acc into own 16-row band of Al as fp16
    #pragma unroll
    for (int j = 0; j < 8; ++j) {
        #pragma unroll
        for (int r = 0; r < 4; ++r)
            Al[16 * w + lk * 4 + r][j * 16 + lr] = (f16)(-accs[j][r]);
    }
    __syncthreads();

    // coalesced store: lane covers 64B of its wave's 4KB band
    const int orow  = 16 * w + (lane >> 2);
    const int grow0 = blk * 64 + orow;
    if (grow0 < kNR) {
        const int q = lane & 3;
        f16* dst = xb + (size_t)grow0 * 128 + q * 32;
        #pragma unroll
        for (int cch = 0; cch < 4; ++cch)
            *(f16x8*)(dst + cch * 8) = *(const f16x8*)&Al[orow][q * 32 + cch * 8];
    }
}

// ---------------------------------------------------------------------------
// k_edge1: per DIRECTED edge j in [0,2*E0): maps2[j] = tanh(a[row]+b[col]),
// adjacency append (1 atomic per directed edge; no diag atomics).
// ---------------------------------------------------------------------------
__global__ __launch_bounds__(256) void k_edge1(
    const int* __restrict__ src, const int* __restrict__ dst,
    const float4* __restrict__ ab, float2* __restrict__ maps2,
    int* __restrict__ cnt, int2* __restrict__ adj)
{
    const int j = blockIdx.x * 256 + threadIdx.x;
    if (j >= kE2) return;
    const bool fwd = j < kE0;
    const int o = fwd ? j : j - kE0;
    const int s = src[o], d = dst[o];
    const int row = fwd ? s : d;
    const int col = fwd ? d : s;
    const float4 ar = ab[row], ac = ab[col];
    const float m0 = tanhf(ar.x + ac.z);
    const float m1 = tanhf(ar.y + ac.w);
    maps2[j] = make_float2(m0, m1);
    const int p = atomicAdd(&cnt[row], 1);
    if (p < kCAP) adj[(size_t)row * kCAP + p] = make_int2(j, col);
}

// ---------------------------------------------------------------------------
// k_diag: per node, walk adjacency, gather maps2, sum m^2 (no atomics).
// Also PADS the adjacency list to a multiple of 8 with sentinel
// (kE2, self) so k_gather runs mask-free (off[kE0] = 0 kills the term).
// ---------------------------------------------------------------------------
__global__ __launch_bounds__(256) void k_diag(
    const int* __restrict__ cnt, int2* __restrict__ adj,
    const float2* __restrict__ maps2, float2* __restrict__ diag)
{
    const int n = blockIdx.x * 256 + threadIdx.x;
    if (n >= kN) return;
    int c = cnt[n];
    if (c > kCAP) c = kCAP;
    int2* al = adj + (size_t)n * kCAP;
    float s0 = 0.f, s1 = 0.f;
    for (int k = 0; k < c; k += 4) {
        const int4 ea = *(const int4*)(al + k);
        const int4 eb = *(const int4*)(al + k + 2);
        const bool v1 = (k + 1 < c), v2 = (k + 2 < c), v3 = (k + 3 < c);
        const int j0 = ea.x;
        const int j1 = v1 ? ea.z : ea.x;
        const int j2 = v2 ? eb.x : ea.x;
        const int j3 = v3 ? eb.z : ea.x;
        const float2 m0 = maps2[j0], m1 = maps2[j1];
        const float2 m2 = maps2[j2], m3 = maps2[j3];
        const float w1 = v1 ? 1.f : 0.f, w2 = v2 ? 1.f : 0.f, w3 = v3 ? 1.f : 0.f;
        s0 += m0.x*m0.x + w1*m1.x*m1.x + w2*m2.x*m2.x + w3*m3.x*m3.x;
        s1 += m0.y*m0.y + w1*m1.y*m1.y + w2*m2.y*m2.y + w3*m3.y*m3.y;
    }
    const int cpad = (c + 7) & ~7;
    for (int k = c; k < cpad; ++k) al[k] = make_int2(kE2, n);
    diag[n] = make_float2(s0, s1);
}

// ---------------------------------------------------------------------------
// k_off: per ORIGINAL edge j: off[j] = -m_fwd*m_bwd * rsqrt((ds+1)(dt+1))
// Thread 0 also writes the sentinel zero entry off[kE0].
// ---------------------------------------------------------------------------
__global__ __launch_bounds__(256) void k_off(
    const int* __restrict__ src, const int* __restrict__ dst,
    const float2* __restrict__ maps2, const float2* __restrict__ diag,
    float2* __restrict__ off)
{
    const int j = blockIdx.x * 256 + threadIdx.x;
    if (j >= kE0) {
        if (j == kE0) off[kE0] = make_float2(0.f, 0.f);
        return;
    }
    if (j == 0) off[kE0] = make_float2(0.f, 0.f);
    const float2 ma = maps2[j];
    const float2 mb = maps2[j + kE0];
    const int s = src[j], d = dst[j];
    const float2 ds = diag[s], dt = diag[d];
    off[j] = make_float2(-ma.x * mb.x * rsqrtf((ds.x + 1.0f) * (dt.x + 1.0f)),
                         -ma.y * mb.y * rsqrtf((ds.y + 1.0f) * (dt.y + 1.0f)));
}

// ---------------------------------------------------------------------------
// k_gather: one wave per node; lane covers (d = lane>>5, h4 = (lane&31)*4)
// 8-wide mask-free MLP loop (adjacency pre-padded to multiple of 8;
// sentinel entries hit off[kE0] = 0 and gather the node's own row).
// ---------------------------------------------------------------------------
__global__ __launch_bounds__(256) void k_gather(
    const f16* __restrict__ xb, const float* __restrict__ diag,
    const float2* __restrict__ off, const int* __restrict__ cnt,
    const int2* __restrict__ adj, float* __restrict__ y)
{
    const int node = blockIdx.x * 4 + (threadIdx.x >> 6);
    const int lane = threadIdx.x & 63;
    const int d    = lane >> 5;
    const int h4   = (lane & 31) << 2;
    const size_t rowoff = ((size_t)node * 2 + d) * 128 + h4;
    const f16x4 own = *(const f16x4*)(xb + rowoff);
    const float dv  = diag[node * 2 + d];
    const float dg  = dv / (dv + 1.0f);             // dis*diag*dis exactly
    f32x4 acc = {dg * (float)own[0], dg * (float)own[1],
                 dg * (float)own[2], dg * (float)own[3]};
    int c = cnt[node];
    if (c > kCAP) c = kCAP;
    const int2* al = adj + (size_t)node * kCAP;

    for (int k = 0; k < c; k += 8) {
        const int4 ea = *(const int4*)(al + k);
        const int4 eb = *(const int4*)(al + k + 2);
        const int4 ec = *(const int4*)(al + k + 4);
        const int4 ed = *(const int4*)(al + k + 6);
        const int jj[8] = {ea.x, ea.z, eb.x, eb.z, ec.x, ec.z, ed.x, ed.z};
        const int nn[8] = {ea.y, ea.w, eb.y, eb.w, ec.y, ec.w, ed.y, ed.w};
        float2 qq[8];
        f16x4  ww[8];
        #pragma unroll
        for (int i = 0; i < 8; ++i) {
            const int oe = jj[i] - (jj[i] >= kE0 ? kE0 : 0);
            qq[i] = off[oe];
            ww[i] = *(const f16x4*)(xb + ((size_t)nn[i] * 2 + d) * 128 + h4);
        }
        #pragma unroll
        for (int i = 0; i < 8; ++i) {
            const float o = d ? qq[i].y : qq[i].x;
            acc[0] += o * (float)ww[i][0];
            acc[1] += o * (float)ww[i][1];
            acc[2] += o * (float)ww[i][2];
            acc[3] += o * (float)ww[i][3];
        }
    }
    __builtin_nontemporal_store(acc, (f32x4*)(y + rowoff));
}

// ---------------------------------------------------------------------------
extern "C" void kernel_launch(void* const* d_in, const int* in_sizes, int n_in,
                              void* d_out, int out_size, void* d_ws, size_t ws_size,
                              hipStream_t stream)
{
    const float* x   = (const float*)d_in[1];
    const int*   src = (const int*)d_in[2];
    const int*   dst = (const int*)d_in[3];
    const float* Wsh = (const float*)d_in[4];
    const float* Wl  = (const float*)d_in[5];
    const float* Wr  = (const float*)d_in[6];

    char* ws = (char*)d_ws;
    f16*    xb    = (f16*)   (ws + 0);           // 25,600,000 B
    float4* ab    = (float4*)(ws + 25600000);    //    800,000 B
    float2* maps2 = (float2*)(ws + 26400000);    //  3,200,000 B (2*E0 float2)
    float2* off   = (float2*)(ws + 29600000);    //  1,600,008 B (kE0+1 entries)
    float2* diag  = (float2*)(ws + 31200016);    //    400,000 B
    int*    cnt   = (int*)   (ws + 31600016);    //    200,000 B
    int2*   adj   = (int2*)  (ws + 31800016);    // 12,800,000 B (kCAP=32)
    f16*    Wrh   = (f16*)   (ws + 44600016);    //     32,768 B

    (void)hipMemsetAsync(cnt, 0, 200000, stream);

    k_wrh   <<<64,   256, 0, stream>>>(Wr, Wrh);
    k_node  <<<1563, 256, 0, stream>>>(x, Wsh, Wl, Wrh, xb, ab);
    k_edge1 <<<1563, 256, 0, stream>>>(src, dst, ab, maps2, cnt, adj);
    k_diag  <<<196,  256, 0, stream>>>(cnt, adj, maps2, diag);
    k_off   <<<783,  256, 0, stream>>>(src, dst, maps2, diag, off);
    k_gather<<<12500, 256, 0, stream>>>(xb, (const float*)diag, off, cnt, adj, (float*)d_out);
}

// Round 9
// 147.687 us; speedup vs baseline: 1.1843x; 1.1843x over previous
//
#include <hip/hip_runtime.h>

static constexpr int kN   = 50000;    // nodes
static constexpr int kNR  = 100000;   // N*D rows
static constexpr int kE0  = 200000;   // original edges
static constexpr int kE2  = 400000;   // directed edges
static constexpr int kCAP = 32;       // adjacency capacity per node (Poisson(8): P(>=32)~7e-11)

typedef _Float16 f16;
typedef f16   f16x8 __attribute__((ext_vector_type(8)));
typedef f16   f16x4 __attribute__((ext_vector_type(4)));
typedef float f32x4 __attribute__((ext_vector_type(4)));

// ---------------------------------------------------------------------------
// k_wrh: one-shot fp32 -> f16 conversion of W_right (128x128, L2-resident)
// ---------------------------------------------------------------------------
__global__ __launch_bounds__(256) void k_wrh(
    const float* __restrict__ Wr, f16* __restrict__ Wrh)
{
    const int i = blockIdx.x * 256 + threadIdx.x;   // 16384 elements
    Wrh[i] = (f16)Wr[i];
}

// ---------------------------------------------------------------------------
// k_node: per block = 32 nodes (64 rows).
//  - computes a[n][2], b[n][2]  (sheaf projections, fp32 wave reductions)
//  - tmp = W_left-mix of x (per row) -> LDS fp16 (A operand only; 17.4 KB)
//  - GEMM: xb[row][c] = - sum_k tmp[row][k] * W_right[c][k] via MFMA f16,
//    B-fragments loaded directly from global Wrh (L2-hot, no LDS, no barrier)
//  - in-wave LDS repack -> coalesced fp16 stores of xb
// ---------------------------------------------------------------------------
__global__ __launch_bounds__(256) void k_node(
    const float* __restrict__ x, const float* __restrict__ Wsh,
    const float* __restrict__ Wl, const f16* __restrict__ Wrh,
    f16* __restrict__ xb, float4* __restrict__ ab)
{
    __shared__ f16 Al[64][136];    // tmp rows / later output repack (+8 pad)

    const int t   = threadIdx.x;
    const int blk = blockIdx.x;

    const float wl00 = Wl[0], wl01 = Wl[1], wl10 = Wl[2], wl11 = Wl[3];

    const int w = t >> 6, lane = t & 63;

    // stage tmp into LDS + compute a/b projections
    #pragma unroll
    for (int i = 0; i < 8; ++i) {
        const int f4   = i * 256 + t;        // float4 index in 64x128 tile
        const int row  = f4 >> 5;            // 0..63
        const int h4   = (f4 & 31) << 2;     // 0..124
        const int grow = blk * 64 + row;
        float4 xo = make_float4(0.f, 0.f, 0.f, 0.f);
        float4 xp = xo;
        if (grow < kNR) {
            xo = *(const float4*)(x + (size_t)grow * 128 + h4);
            xp = *(const float4*)(x + (size_t)(grow ^ 1) * 128 + h4);
        }
        const int dp = row & 1;
        const float  c0 = dp ? wl10 : wl00;
        const float  c1 = dp ? wl11 : wl01;
        const float4 x0 = dp ? xp : xo;      // d2 = 0 data
        const float4 x1 = dp ? xo : xp;      // d2 = 1 data
        Al[row][h4 + 0] = (f16)(c0 * x0.x + c1 * x1.x);
        Al[row][h4 + 1] = (f16)(c0 * x0.y + c1 * x1.y);
        Al[row][h4 + 2] = (f16)(c0 * x0.z + c1 * x1.z);
        Al[row][h4 + 3] = (f16)(c0 * x0.w + c1 * x1.w);

        // a/b partials from OWN float4 (k = dp*128 + h4)
        const int kb = dp * 128 + h4;
        const float4 wa0 = *(const float4*)(Wsh + kb);
        const float4 wb0 = *(const float4*)(Wsh + 256 + kb);
        const float4 wa1 = *(const float4*)(Wsh + 512 + kb);
        const float4 wb1 = *(const float4*)(Wsh + 768 + kb);
        float pa0 = xo.x*wa0.x + xo.y*wa0.y + xo.z*wa0.z + xo.w*wa0.w;
        float pa1 = xo.x*wa1.x + xo.y*wa1.y + xo.z*wa1.z + xo.w*wa1.w;
        float pb0 = xo.x*wb0.x + xo.y*wb0.y + xo.z*wb0.z + xo.w*wb0.w;
        float pb1 = xo.x*wb1.x + xo.y*wb1.y + xo.z*wb1.z + xo.w*wb1.w;
        #pragma unroll
        for (int o = 32; o > 0; o >>= 1) {
            pa0 += __shfl_xor(pa0, o);
            pa1 += __shfl_xor(pa1, o);
            pb0 += __shfl_xor(pb0, o);
            pb1 += __shfl_xor(pb1, o);
        }
        if (lane == 0) {
            const int node = blk * 32 + i * 4 + w;
            if (node < kN) ab[node] = make_float4(pa0, pa1, pb0, pb1);
        }
    }
    __syncthreads();

    // MFMA: each wave does 16 rows x 128 cols, K=128
    const int lr = lane & 15, lk = lane >> 4;
    f16x8 afr[4];
    #pragma unroll
    for (int kk = 0; kk < 4; ++kk)
        afr[kk] = *(const f16x8*)&Al[16 * w + lr][kk * 32 + lk * 8];

    f32x4 accs[8];
    #pragma unroll
    for (int j = 0; j < 8; ++j) {
        f32x4 acc = {0.f, 0.f, 0.f, 0.f};
        #pragma unroll
        for (int kk = 0; kk < 4; ++kk) {
            const f16x8 bfr = *(const f16x8*)(Wrh + (size_t)(j * 16 + lr) * 128 + kk * 32 + lk * 8);
            acc = __builtin_amdgcn_mfma_f32_16x16x32_f16(afr[kk], bfr, acc, 0, 0, 0);
        }
        accs[j] = acc;
    }

    __syncthreads();
    // repack: write -acc into own 16-row band of Al as fp16
    #pragma unroll
    for (int j = 0; j < 8; ++j) {
        #pragma unroll
        for (int r = 0; r < 4; ++r)
            Al[16 * w + lk * 4 + r][j * 16 + lr] = (f16)(-accs[j][r]);
    }
    __syncthreads();

    // coalesced store: lane covers 64B of its wave's 4KB band
    const int orow  = 16 * w + (lane >> 2);
    const int grow0 = blk * 64 + orow;
    if (grow0 < kNR) {
        const int q = lane & 3;
        f16* dst = xb + (size_t)grow0 * 128 + q * 32;
        #pragma unroll
        for (int cch = 0; cch < 4; ++cch)
            *(f16x8*)(dst + cch * 8) = *(const f16x8*)&Al[orow][q * 32 + cch * 8];
    }
}

// ---------------------------------------------------------------------------
// k_edge1: per DIRECTED edge j in [0,2*E0): maps2[j] = tanh(a[row]+b[col]),
// adjacency append (1 atomic per directed edge; no diag atomics).
// ---------------------------------------------------------------------------
__global__ __launch_bounds__(256) void k_edge1(
    const int* __restrict__ src, const int* __restrict__ dst,
    const float4* __restrict__ ab, float2* __restrict__ maps2,
    int* __restrict__ cnt, int2* __restrict__ adj)
{
    const int j = blockIdx.x * 256 + threadIdx.x;
    if (j >= kE2) return;
    const bool fwd = j < kE0;
    const int o = fwd ? j : j - kE0;
    const int s = src[o], d = dst[o];
    const int row = fwd ? s : d;
    const int col = fwd ? d : s;
    const float4 ar = ab[row], ac = ab[col];
    const float m0 = tanhf(ar.x + ac.z);
    const float m1 = tanhf(ar.y + ac.w);
    maps2[j] = make_float2(m0, m1);
    const int p = atomicAdd(&cnt[row], 1);
    if (p < kCAP) adj[(size_t)row * kCAP + p] = make_int2(j, col);
}

// ---------------------------------------------------------------------------
// k_diag: per node, walk adjacency, gather maps2, sum m^2 (no atomics).
// Also PADS the adjacency list to a multiple of 8 with sentinel
// (kE2, self) so k_gather runs mask-free (off[kE0] = 0 kills the term).
// ---------------------------------------------------------------------------
__global__ __launch_bounds__(256) void k_diag(
    const int* __restrict__ cnt, int2* __restrict__ adj,
    const float2* __restrict__ maps2, float2* __restrict__ diag)
{
    const int n = blockIdx.x * 256 + threadIdx.x;
    if (n >= kN) return;
    int c = cnt[n];
    if (c > kCAP) c = kCAP;
    int2* al = adj + (size_t)n * kCAP;
    float s0 = 0.f, s1 = 0.f;
    for (int k = 0; k < c; k += 4) {
        const int4 ea = *(const int4*)(al + k);
        const int4 eb = *(const int4*)(al + k + 2);
        const bool v1 = (k + 1 < c), v2 = (k + 2 < c), v3 = (k + 3 < c);
        const int j0 = ea.x;
        const int j1 = v1 ? ea.z : ea.x;
        const int j2 = v2 ? eb.x : ea.x;
        const int j3 = v3 ? eb.z : ea.x;
        const float2 m0 = maps2[j0], m1 = maps2[j1];
        const float2 m2 = maps2[j2], m3 = maps2[j3];
        const float w1 = v1 ? 1.f : 0.f, w2 = v2 ? 1.f : 0.f, w3 = v3 ? 1.f : 0.f;
        s0 += m0.x*m0.x + w1*m1.x*m1.x + w2*m2.x*m2.x + w3*m3.x*m3.x;
        s1 += m0.y*m0.y + w1*m1.y*m1.y + w2*m2.y*m2.y + w3*m3.y*m3.y;
    }
    const int cpad = (c + 7) & ~7;
    for (int k = c; k < cpad; ++k) al[k] = make_int2(kE2, n);
    diag[n] = make_float2(s0, s1);
}

// ---------------------------------------------------------------------------
// k_off: per ORIGINAL edge j: off[j] = -m_fwd*m_bwd * rsqrt((ds+1)(dt+1))
// Thread kE0 also writes the sentinel zero entry off[kE0].
// ---------------------------------------------------------------------------
__global__ __launch_bounds__(256) void k_off(
    const int* __restrict__ src, const int* __restrict__ dst,
    const float2* __restrict__ maps2, const float2* __restrict__ diag,
    float2* __restrict__ off)
{
    const int j = blockIdx.x * 256 + threadIdx.x;
    if (j >= kE0) {
        if (j == kE0) off[kE0] = make_float2(0.f, 0.f);
        return;
    }
    const float2 ma = maps2[j];
    const float2 mb = maps2[j + kE0];
    const int s = src[j], d = dst[j];
    const float2 ds = diag[s], dt = diag[d];
    off[j] = make_float2(-ma.x * mb.x * rsqrtf((ds.x + 1.0f) * (dt.x + 1.0f)),
                         -ma.y * mb.y * rsqrtf((ds.y + 1.0f) * (dt.y + 1.0f)));
}

// ---------------------------------------------------------------------------
// k_gather: one wave per node; lane covers (d = lane>>5, h4 = (lane&31)*4)
// 8-wide mask-free MLP loop, ALL NAMED SCALARS (no private arrays —
// avoids AMDGPUPromoteAlloca putting them in LDS, the round-8 regression).
// ---------------------------------------------------------------------------
__global__ __launch_bounds__(256) void k_gather(
    const f16* __restrict__ xb, const float* __restrict__ diag,
    const float2* __restrict__ off, const int* __restrict__ cnt,
    const int2* __restrict__ adj, float* __restrict__ y)
{
    const int node = blockIdx.x * 4 + (threadIdx.x >> 6);
    const int lane = threadIdx.x & 63;
    const int d    = lane >> 5;
    const int h4   = (lane & 31) << 2;
    const size_t rowoff = ((size_t)node * 2 + d) * 128 + h4;
    const f16x4 own = *(const f16x4*)(xb + rowoff);
    const float dv  = diag[node * 2 + d];
    const float dg  = dv / (dv + 1.0f);             // dis*diag*dis exactly
    f32x4 acc = {dg * (float)own[0], dg * (float)own[1],
                 dg * (float)own[2], dg * (float)own[3]};
    int c = cnt[node];
    if (c > kCAP) c = kCAP;
    const int2* al = adj + (size_t)node * kCAP;

    for (int k = 0; k < c; k += 8) {
        const int4 ea = *(const int4*)(al + k);
        const int4 eb = *(const int4*)(al + k + 2);
        const int4 ec = *(const int4*)(al + k + 4);
        const int4 ed = *(const int4*)(al + k + 6);
        const int j0 = ea.x, n0 = ea.y, j1 = ea.z, n1 = ea.w;
        const int j2 = eb.x, n2 = eb.y, j3 = eb.z, n3 = eb.w;
        const int j4 = ec.x, n4 = ec.y, j5 = ec.z, n5 = ec.w;
        const int j6 = ed.x, n6 = ed.y, j7 = ed.z, n7 = ed.w;
        const float2 q0 = off[j0 - (j0 >= kE0 ? kE0 : 0)];
        const float2 q1 = off[j1 - (j1 >= kE0 ? kE0 : 0)];
        const float2 q2 = off[j2 - (j2 >= kE0 ? kE0 : 0)];
        const float2 q3 = off[j3 - (j3 >= kE0 ? kE0 : 0)];
        const float2 q4 = off[j4 - (j4 >= kE0 ? kE0 : 0)];
        const float2 q5 = off[j5 - (j5 >= kE0 ? kE0 : 0)];
        const float2 q6 = off[j6 - (j6 >= kE0 ? kE0 : 0)];
        const float2 q7 = off[j7 - (j7 >= kE0 ? kE0 : 0)];
        const f16x4 w0 = *(const f16x4*)(xb + ((size_t)n0 * 2 + d) * 128 + h4);
        const f16x4 w1 = *(const f16x4*)(xb + ((size_t)n1 * 2 + d) * 128 + h4);
        const f16x4 w2 = *(const f16x4*)(xb + ((size_t)n2 * 2 + d) * 128 + h4);
        const f16x4 w3 = *(const f16x4*)(xb + ((size_t)n3 * 2 + d) * 128 + h4);
        const f16x4 w4 = *(const f16x4*)(xb + ((size_t)n4 * 2 + d) * 128 + h4);
        const f16x4 w5 = *(const f16x4*)(xb + ((size_t)n5 * 2 + d) * 128 + h4);
        const f16x4 w6 = *(const f16x4*)(xb + ((size_t)n6 * 2 + d) * 128 + h4);
        const f16x4 w7 = *(const f16x4*)(xb + ((size_t)n7 * 2 + d) * 128 + h4);
        const float o0 = d ? q0.y : q0.x;
        const float o1 = d ? q1.y : q1.x;
        const float o2 = d ? q2.y : q2.x;
        const float o3 = d ? q3.y : q3.x;
        const float o4 = d ? q4.y : q4.x;
        const float o5 = d ? q5.y : q5.x;
        const float o6 = d ? q6.y : q6.x;
        const float o7 = d ? q7.y : q7.x;
        #pragma unroll
        for (int i = 0; i < 4; ++i) {
            float s = o0 * (float)w0[i] + o1 * (float)w1[i];
            s += o2 * (float)w2[i] + o3 * (float)w3[i];
            s += o4 * (float)w4[i] + o5 * (float)w5[i];
            s += o6 * (float)w6[i] + o7 * (float)w7[i];
            acc[i] += s;
        }
    }
    __builtin_nontemporal_store(acc, (f32x4*)(y + rowoff));
}

// ---------------------------------------------------------------------------
extern "C" void kernel_launch(void* const* d_in, const int* in_sizes, int n_in,
                              void* d_out, int out_size, void* d_ws, size_t ws_size,
                              hipStream_t stream)
{
    const float* x   = (const float*)d_in[1];
    const int*   src = (const int*)d_in[2];
    const int*   dst = (const int*)d_in[3];
    const float* Wsh = (const float*)d_in[4];
    const float* Wl  = (const float*)d_in[5];
    const float* Wr  = (const float*)d_in[6];

    char* ws = (char*)d_ws;
    f16*    xb    = (f16*)   (ws + 0);           // 25,600,000 B
    float4* ab    = (float4*)(ws + 25600000);    //    800,000 B
    float2* maps2 = (float2*)(ws + 26400000);    //  3,200,000 B (2*E0 float2)
    float2* off   = (float2*)(ws + 29600000);    //  1,600,008 B (kE0+1 entries)
    float2* diag  = (float2*)(ws + 31200016);    //    400,000 B
    int*    cnt   = (int*)   (ws + 31600016);    //    200,000 B
    int2*   adj   = (int2*)  (ws + 31800016);    // 12,800,000 B (kCAP=32)
    f16*    Wrh   = (f16*)   (ws + 44600016);    //     32,768 B

    (void)hipMemsetAsync(cnt, 0, 200000, stream);

    k_wrh   <<<64,   256, 0, stream>>>(Wr, Wrh);
    k_node  <<<1563, 256, 0, stream>>>(x, Wsh, Wl, Wrh, xb, ab);
    k_edge1 <<<1563, 256, 0, stream>>>(src, dst, ab, maps2, cnt, adj);
    k_diag  <<<196,  256, 0, stream>>>(cnt, adj, maps2, diag);
    k_off   <<<783,  256, 0, stream>>>(src, dst, maps2, diag, off);
    k_gather<<<12500, 256, 0, stream>>>(xb, (const float*)diag, off, cnt, adj, (float*)d_out);
}